// Round 6
// baseline (249.447 us; speedup 1.0000x reference)
//
#include <hip/hip_runtime.h>
#include <math.h>

#define D_PROJ 8192
#define C_IN   512
#define P_SP   196   // 14*14
#define NBATCH 32
#define CAP    96    // bucket capacity (mean 32, P(>=96) ~ e^-41 per bin)

// ---------------------------------------------------------------------------
// Recover both count-sketches: S1,S2 [512,8192], one nonzero (+-1) per row.
// Writes packed  h | (s<0 ? 0x8000 : 0).
// ---------------------------------------------------------------------------
__global__ __launch_bounds__(256) void extract_both(
    const float* __restrict__ S1, const float* __restrict__ S2,
    int* __restrict__ p1, int* __restrict__ p2)
{
    const int total4 = 2 * C_IN * (D_PROJ / 4);      // 2,097,152 float4
    for (int idx = blockIdx.x * 256 + threadIdx.x; idx < total4;
         idx += 1024 * 256) {
        const int m   = idx >> 20;                   // 0: S1, 1: S2
        const int rem = idx & 1048575;
        const float4 v = ((const float4*)(m ? S2 : S1))[rem];
        if (v.x != 0.f || v.y != 0.f || v.z != 0.f || v.w != 0.f) {
            const int row = rem >> 11;               // 2048 float4 / row
            const int c4  = (rem & 2047) << 2;
            float val; int c;
            if      (v.x != 0.f) { val = v.x; c = c4;     }
            else if (v.y != 0.f) { val = v.y; c = c4 + 1; }
            else if (v.z != 0.f) { val = v.z; c = c4 + 2; }
            else                 { val = v.w; c = c4 + 3; }
            (m ? p2 : p1)[row] = c | (val < 0.f ? 0x8000 : 0);
        }
    }
}

// ---------------------------------------------------------------------------
// Bucket build: for every ordered pair (i,j), bin d=(h1[i]+h2[j])&8191,
// record = i | j<<9 | sign<<18 appended via one global atomic on counts[d].
// Bin pattern is batch-independent -- computed ONCE here instead of paying
// 16.8M LDS atomics in the hot kernel (the R1-R5 ~110 us invariant).
// ---------------------------------------------------------------------------
__global__ __launch_bounds__(256) void build_buckets(
    const int* __restrict__ p1, const int* __restrict__ p2,
    int* __restrict__ counts, unsigned int* __restrict__ buckets)
{
    const int i  = blockIdx.x;
    const int v1 = p1[i];
    const int h1 = v1 & 8191;
    const int g1 = (v1 >> 15) & 1;
    for (int j = threadIdx.x; j < C_IN; j += 256) {
        const int v2 = p2[j];
        const int d  = (h1 + (v2 & 8191)) & (D_PROJ - 1);
        const unsigned int rec = (unsigned int)i | ((unsigned int)j << 9)
            | ((unsigned int)((g1 ^ ((v2 >> 15) & 1)) & 1) << 18);
        const int idx = atomicAdd(&counts[d], 1);
        if (idx < CAP) buckets[d * CAP + idx] = rec;   // clamp for safety
    }
}

// ---------------------------------------------------------------------------
// Batched Gram GEMM: G[i][j][b] = sum_p x[b,i,p] x[b,j,p].  Pure GEMM — no
// histogram, no atomics.  Block=(b fastest, tile); 128x128 tile, 8x8 micro,
// BK=28.  Staged directly from x (p-contiguous rows) with a transposing LDS
// write; LDA=132 keeps the p-major layout 16B-row-aligned, conflicts <=4-way.
// Epilogue: scattered 4B stores into [i][j][b]; b-fastest grid ordering makes
// the 32 batch-stores per 128B line temporally adjacent in L2.
// ---------------------------------------------------------------------------
#define BK  28
#define LDA 132

__global__ __launch_bounds__(256) void gram_gemm(
    const float* __restrict__ x, float* __restrict__ G)
{
    __shared__ __align__(16) float As[BK * LDA];     // 14784 B
    __shared__ __align__(16) float Bs[BK * LDA];

    const int tid  = threadIdx.x;
    const int b    = blockIdx.x;                     // batch (fastest)
    const int tile = blockIdx.y;
    const int it   = tile >> 2, jt = tile & 3;
    const int tx   = tid & 15, ty = tid >> 4;

    const float* xi = x + ((size_t)b * C_IN + it * 128) * P_SP;
    const float* xj = x + ((size_t)b * C_IN + jt * 128) * P_SP;

    float acc[8][8];
    #pragma unroll
    for (int r = 0; r < 8; ++r)
        #pragma unroll
        for (int c = 0; c < 8; ++c) acc[r][c] = 0.0f;

    for (int ck = 0; ck < 7; ++ck) {
        const int p0 = ck * BK;
        __syncthreads();
        // stage 896 float4 per operand: f4 -> row c=f4/7, quad k4=f4%7
        #pragma unroll
        for (int k = 0; k < 4; ++k) {
            const int f4 = k * 256 + tid;
            if (f4 < 896) {
                const int c  = f4 / 7;
                const int k4 = f4 - c * 7;
                const float4 va = *(const float4*)(xi + c * P_SP + p0 + k4 * 4);
                const float4 vb = *(const float4*)(xj + c * P_SP + p0 + k4 * 4);
                const int pb = k4 * 4;
                As[(pb + 0) * LDA + c] = va.x; As[(pb + 1) * LDA + c] = va.y;
                As[(pb + 2) * LDA + c] = va.z; As[(pb + 3) * LDA + c] = va.w;
                Bs[(pb + 0) * LDA + c] = vb.x; Bs[(pb + 1) * LDA + c] = vb.y;
                Bs[(pb + 2) * LDA + c] = vb.z; Bs[(pb + 3) * LDA + c] = vb.w;
            }
        }
        __syncthreads();
        #pragma unroll 4
        for (int p = 0; p < BK; ++p) {
            const float* ap = As + p * LDA;
            const float* bp = Bs + p * LDA;
            const float4 a0 = *(const float4*)(ap + ty * 4);
            const float4 a1 = *(const float4*)(ap + 64 + ty * 4);
            const float4 b0 = *(const float4*)(bp + tx * 4);
            const float4 b1 = *(const float4*)(bp + 64 + tx * 4);
            const float av[8] = {a0.x, a0.y, a0.z, a0.w, a1.x, a1.y, a1.z, a1.w};
            const float bv[8] = {b0.x, b0.y, b0.z, b0.w, b1.x, b1.y, b1.z, b1.w};
            #pragma unroll
            for (int r = 0; r < 8; ++r)
                #pragma unroll
                for (int c = 0; c < 8; ++c)
                    acc[r][c] = fmaf(av[r], bv[c], acc[r][c]);
        }
    }

    // epilogue: G[i][j][b] scattered 4B stores
    #pragma unroll
    for (int r = 0; r < 8; ++r) {
        const int i = it * 128 + ((r < 4) ? (ty * 4 + r) : (64 + ty * 4 + r - 4));
        #pragma unroll
        for (int c = 0; c < 8; ++c) {
            const int j = jt * 128 + ((c < 4) ? (tx * 4 + c) : (64 + tx * 4 + c - 4));
            G[((((size_t)i << 9) + j) << 5) + b] = acc[r][c];
        }
    }
}

// ---------------------------------------------------------------------------
// Gather: one wave per bin d.  Each record's G[i,j,0:32] is one contiguous
// 128B vector -> every G element is read exactly once, coalesced, no atomics.
// Lane layout: slot parity = lane>>5, batch = lane&31.
// ---------------------------------------------------------------------------
__global__ __launch_bounds__(256) void gather_pool(
    const int* __restrict__ counts, const unsigned int* __restrict__ buckets,
    const float* __restrict__ G, float* __restrict__ pool)
{
    const int d    = blockIdx.x * 4 + (threadIdx.x >> 6);
    const int lane = threadIdx.x & 63;
    const int r2   = lane >> 5;
    const int bb   = lane & 31;

    int n = counts[d];
    if (n > CAP) n = CAP;
    const unsigned int* bk = buckets + d * CAP;

    float acc = 0.0f;
    #pragma unroll 4
    for (int k = 0; k < n; k += 2) {
        const int slot = k + r2;
        if (slot < n) {
            const unsigned int rec = bk[slot];
            const int i = rec & 511;
            const int j = (rec >> 9) & 511;
            float v = G[((((size_t)i << 9) + j) << 5) + bb];
            acc += (rec & (1u << 18)) ? -v : v;
        }
    }
    acc += __shfl_xor(acc, 32, 64);
    if (lane < 32) pool[d * 32 + bb] = acc;   // pool layout [d][b]
}

// ---------------------------------------------------------------------------
// Finalize per batch: total = sum_d |pool[d][b]|;
// out[b][d] = sign * sqrt(|.|+1e-8) / max(sqrt(total + 8192e-8), 1e-12).
// ---------------------------------------------------------------------------
__global__ __launch_bounds__(256) void finalize_kernel(
    const float* __restrict__ pool, float* __restrict__ out)
{
    const int b   = blockIdx.x;
    const int tid = threadIdx.x;

    float vals[32];
    float s = 0.0f;
    #pragma unroll
    for (int k = 0; k < 32; ++k) {
        const float v = pool[(size_t)(k * 256 + tid) * 32 + b];
        vals[k] = v;
        s += fabsf(v);
    }
    #pragma unroll
    for (int off = 32; off > 0; off >>= 1) s += __shfl_down(s, off, 64);

    __shared__ float red[4];
    if ((tid & 63) == 0) red[tid >> 6] = s;
    __syncthreads();
    const float total = red[0] + red[1] + red[2] + red[3];
    const float inv =
        1.0f / fmaxf(sqrtf(total + (float)D_PROJ * 1e-8f), 1e-12f);

    float* ob = out + (size_t)b * D_PROJ;
    #pragma unroll
    for (int k = 0; k < 32; ++k) {
        const float v = vals[k];
        const float r = sqrtf(fabsf(v) + 1e-8f) * inv;
        ob[k * 256 + tid] = (v > 0.f) ? r : ((v < 0.f) ? -r : 0.f);
    }
}

// ---------------------------------------------------------------------------
extern "C" void kernel_launch(void* const* d_in, const int* in_sizes, int n_in,
                              void* d_out, int out_size, void* d_ws, size_t ws_size,
                              hipStream_t stream)
{
    const float* x  = (const float*)d_in[0];   // [32, 512, 14, 14]
    const float* S1 = (const float*)d_in[1];   // [512, 8192]
    const float* S2 = (const float*)d_in[2];   // [512, 8192]
    float* out = (float*)d_out;                // [32, 8192]

    char* ws = (char*)d_ws;
    int*          p1      = (int*)(ws);                  // 2 KB
    int*          p2      = (int*)(ws + 2048);           // 2 KB
    int*          counts  = (int*)(ws + 4096);           // 32 KB
    float*        pool    = (float*)(ws + 36864);        // 1 MB   [d][b]
    unsigned int* buckets = (unsigned int*)(ws + 1085440);   // 3 MB (8192*96)
    float*        G       = (float*)(ws + 4231168);      // 33.5 MB [i][j][b]

    hipMemsetAsync(counts, 0, D_PROJ * sizeof(int), stream);
    extract_both<<<1024, 256, 0, stream>>>(S1, S2, p1, p2);
    build_buckets<<<C_IN, 256, 0, stream>>>(p1, p2, counts, buckets);
    gram_gemm<<<dim3(NBATCH, 16), 256, 0, stream>>>(x, G);
    gather_pool<<<D_PROJ / 4, 256, 0, stream>>>(counts, buckets, G, pool);
    finalize_kernel<<<NBATCH, 256, 0, stream>>>(pool, out);
}